// Round 4
// baseline (1429.148 us; speedup 1.0000x reference)
//
#include <hip/hip_runtime.h>
#include <math.h>

#define NN 100000
#define NE 1600000
#define D 128

#define BSZ 128                         // dst-nodes per bucket
#define NB ((NN + BSZ - 1) / BSZ)       // 782 buckets
#define CHUNK 4096                      // edges per partition block
#define NBLK ((NE + CHUNK - 1) / CHUNK) // 391

#define BM 64            // rows per block in MFMA GEMM
#define LDT 136          // padded LDS row stride (bf16 units)

typedef __attribute__((ext_vector_type(8))) short bf16x8;
typedef __attribute__((ext_vector_type(4))) float f32x4;

__device__ __forceinline__ unsigned short f2bf(float f) {
    unsigned int u = __builtin_bit_cast(unsigned int, f);
    unsigned int r = (u + 0x7FFFu + ((u >> 16) & 1u)) >> 16;   // RTNE
    return (unsigned short)r;
}

// ---------------------------------------------------------------------------
// MFMA GEMM: h = bf16(x) @ bf16(W)^T, fp32 accumulate, bf16 output. Unchanged.
// ---------------------------------------------------------------------------
__global__ __launch_bounds__(256) void mfma_gemm_kernel(const float* __restrict__ x,
                                                        const float* __restrict__ W,
                                                        unsigned short* __restrict__ h) {
    __shared__ __align__(16) unsigned short lA[BM * LDT];
    __shared__ __align__(16) unsigned short lB[128 * LDT];
    const int tid = threadIdx.x;
    const int rowBase = blockIdx.x * BM;

#pragma unroll
    for (int i = 0; i < 16; ++i) {
        int f = tid + 256 * i;
        int r = f >> 5, c4 = f & 31;
        float4 v = *reinterpret_cast<const float4*>(W + (size_t)r * D + c4 * 4);
        ushort4 b;
        b.x = f2bf(v.x); b.y = f2bf(v.y); b.z = f2bf(v.z); b.w = f2bf(v.w);
        *reinterpret_cast<ushort4*>(&lB[r * LDT + c4 * 4]) = b;
    }
#pragma unroll
    for (int i = 0; i < 8; ++i) {
        int f = tid + 256 * i;
        int r = f >> 5, c4 = f & 31;
        int gr = rowBase + r;
        float4 v = {0.f, 0.f, 0.f, 0.f};
        if (gr < NN) v = *reinterpret_cast<const float4*>(x + (size_t)gr * D + c4 * 4);
        ushort4 b;
        b.x = f2bf(v.x); b.y = f2bf(v.y); b.z = f2bf(v.z); b.w = f2bf(v.w);
        *reinterpret_cast<ushort4*>(&lA[r * LDT + c4 * 4]) = b;
    }
    __syncthreads();

    const int lane = tid & 63;
    const int w = tid >> 6;
    const int l16 = lane & 15;
    const int koff = (lane >> 4) * 8;

    f32x4 acc[8];
#pragma unroll
    for (int j = 0; j < 8; ++j) acc[j] = (f32x4){0.f, 0.f, 0.f, 0.f};

    const int arow = w * 16 + l16;
#pragma unroll
    for (int kk = 0; kk < 4; ++kk) {
        int kbase = kk * 32 + koff;
        bf16x8 a = *reinterpret_cast<const bf16x8*>(&lA[arow * LDT + kbase]);
#pragma unroll
        for (int j = 0; j < 8; ++j) {
            bf16x8 b = *reinterpret_cast<const bf16x8*>(&lB[(j * 16 + l16) * LDT + kbase]);
            acc[j] = __builtin_amdgcn_mfma_f32_16x16x32_bf16(a, b, acc[j], 0, 0, 0);
        }
    }

    const int crow0 = rowBase + w * 16 + (lane >> 4) * 4;
#pragma unroll
    for (int j = 0; j < 8; ++j) {
        int col = j * 16 + l16;
#pragma unroll
        for (int q = 0; q < 4; ++q) {
            int gr = crow0 + q;
            if (gr < NN) h[(size_t)gr * D + col] = f2bf(acc[j][q]);
        }
    }
}

// ---------------------------------------------------------------------------
// Bucket count: LDS histogram per block, one global atomic per (block,bucket).
// ---------------------------------------------------------------------------
__global__ __launch_bounds__(256) void count_kernel(const int* __restrict__ dst,
                                                    int* __restrict__ bucketCnt) {
    __shared__ int cnt[NB];
    int t = threadIdx.x;
    for (int i = t; i < NB; i += 256) cnt[i] = 0;
    __syncthreads();
    int cb = blockIdx.x * CHUNK;
#pragma unroll
    for (int i = 0; i < CHUNK / 256; ++i) {
        int e = cb + t + 256 * i;
        if (e < NE) atomicAdd(&cnt[dst[e] >> 7], 1);
    }
    __syncthreads();
    for (int i = t; i < NB; i += 256)
        if (cnt[i]) atomicAdd(&bucketCnt[i], cnt[i]);
}

// ---------------------------------------------------------------------------
// Exclusive scan of NB bucket counts (single block, 256 thr x 4 each).
// ---------------------------------------------------------------------------
__global__ __launch_bounds__(256) void scan_kernel(const int* __restrict__ bucketCnt,
                                                   int* __restrict__ bucketPtr,
                                                   int* __restrict__ bucketCursor) {
    __shared__ int lsc[256];
    int t = threadIdx.x;
    int c[4];
    int s = 0;
#pragma unroll
    for (int i = 0; i < 4; ++i) {
        int b = 4 * t + i;
        c[i] = (b < NB) ? bucketCnt[b] : 0;
        s += c[i];
    }
    lsc[t] = s;
    __syncthreads();
    for (int off = 1; off < 256; off <<= 1) {
        int v = (t >= off) ? lsc[t - off] : 0;
        __syncthreads();
        lsc[t] += v;
        __syncthreads();
    }
    int run = lsc[t] - s;   // exclusive prefix of this thread's group
#pragma unroll
    for (int i = 0; i < 4; ++i) {
        int b = 4 * t + i;
        if (b < NB) { bucketPtr[b] = run; bucketCursor[b] = run; }
        run += c[i];
    }
    if (t == 0) bucketPtr[NB] = NE;
}

// ---------------------------------------------------------------------------
// Multi-split scatter: LDS-staged reorder so global writes are per-bucket
// contiguous runs (line-merged). Record: x = src | (dstLocal<<17), y = val.
// ---------------------------------------------------------------------------
__global__ __launch_bounds__(256) void scatter_kernel(const int* __restrict__ src,
                                                      const int* __restrict__ dst,
                                                      const float* __restrict__ vals,
                                                      int* __restrict__ bucketCursor,
                                                      uint2* __restrict__ ebuf) {
    __shared__ int l_start[NB];
    __shared__ int l_cur[NB];
    __shared__ int l_gbase[NB];
    __shared__ int l_scan[256];
    __shared__ uint2 s_rec[CHUNK];
    __shared__ int s_gd[CHUNK];

    int t = threadIdx.x;
    int cb = blockIdx.x * CHUNK;
    int nloc = min(CHUNK, NE - cb);

    // 1. local histogram
    for (int i = t; i < NB; i += 256) l_cur[i] = 0;
    __syncthreads();
#pragma unroll
    for (int i = 0; i < CHUNK / 256; ++i) {
        int e = cb + t + 256 * i;
        if (e < NE) atomicAdd(&l_cur[dst[e] >> 7], 1);
    }
    __syncthreads();

    // 2. local exclusive scan + global base reservation
    int c[4];
    int s = 0;
#pragma unroll
    for (int i = 0; i < 4; ++i) {
        int b = 4 * t + i;
        c[i] = (b < NB) ? l_cur[b] : 0;
        s += c[i];
    }
    l_scan[t] = s;
    __syncthreads();
    for (int off = 1; off < 256; off <<= 1) {
        int v = (t >= off) ? l_scan[t - off] : 0;
        __syncthreads();
        l_scan[t] += v;
        __syncthreads();
    }
    int run = l_scan[t] - s;
#pragma unroll
    for (int i = 0; i < 4; ++i) {
        int b = 4 * t + i;
        if (b < NB) {
            l_start[b] = run;
            l_cur[b]   = run;
            l_gbase[b] = c[i] ? atomicAdd(&bucketCursor[b], c[i]) : 0;
        }
        run += c[i];
    }
    __syncthreads();

    // 3. reorder records into LDS by bucket
#pragma unroll
    for (int i = 0; i < CHUNK / 256; ++i) {
        int e = cb + t + 256 * i;
        if (e < NE) {
            int dn = dst[e];
            int b = dn >> 7;
            uint2 rec;
            rec.x = (unsigned int)src[e] | ((unsigned int)(dn & 127) << 17);
            rec.y = __float_as_uint(vals[e]);
            int lofs = atomicAdd(&l_cur[b], 1);
            s_rec[lofs] = rec;
            s_gd[lofs] = l_gbase[b] + (lofs - l_start[b]);
        }
    }
    __syncthreads();

    // 4. flush: consecutive staged slots -> consecutive global (per run)
#pragma unroll
    for (int i = 0; i < CHUNK / 256; ++i) {
        int j = t + 256 * i;
        if (j < nloc) ebuf[s_gd[j]] = s_rec[j];
    }
}

// ---------------------------------------------------------------------------
// Pull: one block per bucket; 64KB LDS fp32 accumulator (128 nodes x 128 d).
// Wave w handles edges beg+w, beg+w+8, ...; 64 lanes cover dims {l, l+64}
// (stride-4B ds_add -> 2-way bank aliasing = free). Fused exact GELU.
// ---------------------------------------------------------------------------
__global__ __launch_bounds__(512) void pull_kernel(const unsigned short* __restrict__ h,
                                                   const int* __restrict__ bucketPtr,
                                                   const uint2* __restrict__ ebuf,
                                                   float* __restrict__ out) {
    __shared__ float acc[BSZ * D];   // 64 KB
    int t = threadIdx.x;
    int b = blockIdx.x;
    int base = b * BSZ;

    float4* a4 = reinterpret_cast<float4*>(acc);
#pragma unroll
    for (int i = 0; i < (BSZ * D / 4) / 512; ++i)
        a4[t + 512 * i] = (float4){0.f, 0.f, 0.f, 0.f};
    __syncthreads();

    int beg = bucketPtr[b];
    int end = bucketPtr[b + 1];
    int lane = t & 63;
    int w = t >> 6;

    for (int e = beg + w; e < end; e += 8) {
        uint2 rec = ebuf[e];
        int   srcn = rec.x & 0x1FFFF;
        int   dl   = (rec.x >> 17) & 127;
        float val  = __uint_as_float(rec.y);
        const unsigned short* hr = h + (size_t)srcn * D;
        float h0 = __uint_as_float((unsigned int)hr[lane] << 16);
        float h1 = __uint_as_float((unsigned int)hr[lane + 64] << 16);
        atomicAdd(&acc[dl * D + lane],      val * h0);
        atomicAdd(&acc[dl * D + lane + 64], val * h1);
    }
    __syncthreads();

    int nLoc = min(BSZ, NN - base);
    const float is2 = 0.70710678118654752f;
    for (int f = t; f < nLoc * D; f += 512) {
        float a = acc[f];
        a = 0.5f * a * (1.f + erff(a * is2));
        out[(size_t)base * D + f] = a;
    }
}

extern "C" void kernel_launch(void* const* d_in, const int* in_sizes, int n_in,
                              void* d_out, int out_size, void* d_ws, size_t ws_size,
                              hipStream_t stream) {
    const float* x    = (const float*)d_in[0];
    const float* W    = (const float*)d_in[1];
    const float* vals = (const float*)d_in[2];
    const int*   src  = (const int*)d_in[3];
    const int*   dst  = (const int*)d_in[4];
    float* out = (float*)d_out;

    // Workspace: h bf16 (25.6MB) | bucketCnt | bucketPtr | bucketCursor | ebuf (12.8MB)
    char* ws = (char*)d_ws;
    size_t off = 0;
    unsigned short* h = (unsigned short*)(ws + off); off += (size_t)NN * D * 2;
    int* bucketCnt    = (int*)(ws + off); off += ((size_t)NB + 4) * 4;
    int* bucketPtr    = (int*)(ws + off); off += ((size_t)NB + 4) * 4;
    int* bucketCursor = (int*)(ws + off); off += ((size_t)NB + 4) * 4;
    off = (off + 15) & ~(size_t)15;
    uint2* ebuf       = (uint2*)(ws + off); off += (size_t)NE * 8;

    hipMemsetAsync(bucketCnt, 0, ((size_t)NB + 4) * 4, stream);

    mfma_gemm_kernel<<<(NN + BM - 1) / BM, 256, 0, stream>>>(x, W, h);

    count_kernel<<<NBLK, 256, 0, stream>>>(dst, bucketCnt);
    scan_kernel<<<1, 256, 0, stream>>>(bucketCnt, bucketPtr, bucketCursor);
    scatter_kernel<<<NBLK, 256, 0, stream>>>(src, dst, vals, bucketCursor, ebuf);

    pull_kernel<<<NB, 512, 0, stream>>>(h, bucketPtr, ebuf, out);
}

// Round 5
// 227.432 us; speedup vs baseline: 6.2839x; 6.2839x over previous
//
#include <hip/hip_runtime.h>
#include <math.h>

#define NN 100000
#define NE 1600000
#define D 128

#define BSZ 128                         // dst-nodes per bucket
#define NB ((NN + BSZ - 1) / BSZ)       // 782 buckets
#define CHUNK 4096                      // edges per partition block
#define NBLK ((NE + CHUNK - 1) / CHUNK) // 391
#define CAP 2560                        // sorted-records tile per bucket (avg 2046)

#define BM 64            // rows per block in MFMA GEMM
#define LDT 136          // padded LDS row stride (bf16 units)

typedef __attribute__((ext_vector_type(8))) short bf16x8;
typedef __attribute__((ext_vector_type(4))) float f32x4;

__device__ __forceinline__ unsigned short f2bf(float f) {
    unsigned int u = __builtin_bit_cast(unsigned int, f);
    unsigned int r = (u + 0x7FFFu + ((u >> 16) & 1u)) >> 16;   // RTNE
    return (unsigned short)r;
}

// ---------------------------------------------------------------------------
// MFMA GEMM: h = bf16(x) @ bf16(W)^T, fp32 accumulate, bf16 output.
// ---------------------------------------------------------------------------
__global__ __launch_bounds__(256) void mfma_gemm_kernel(const float* __restrict__ x,
                                                        const float* __restrict__ W,
                                                        unsigned short* __restrict__ h) {
    __shared__ __align__(16) unsigned short lA[BM * LDT];
    __shared__ __align__(16) unsigned short lB[128 * LDT];
    const int tid = threadIdx.x;
    const int rowBase = blockIdx.x * BM;

#pragma unroll
    for (int i = 0; i < 16; ++i) {
        int f = tid + 256 * i;
        int r = f >> 5, c4 = f & 31;
        float4 v = *reinterpret_cast<const float4*>(W + (size_t)r * D + c4 * 4);
        ushort4 b;
        b.x = f2bf(v.x); b.y = f2bf(v.y); b.z = f2bf(v.z); b.w = f2bf(v.w);
        *reinterpret_cast<ushort4*>(&lB[r * LDT + c4 * 4]) = b;
    }
#pragma unroll
    for (int i = 0; i < 8; ++i) {
        int f = tid + 256 * i;
        int r = f >> 5, c4 = f & 31;
        int gr = rowBase + r;
        float4 v = {0.f, 0.f, 0.f, 0.f};
        if (gr < NN) v = *reinterpret_cast<const float4*>(x + (size_t)gr * D + c4 * 4);
        ushort4 b;
        b.x = f2bf(v.x); b.y = f2bf(v.y); b.z = f2bf(v.z); b.w = f2bf(v.w);
        *reinterpret_cast<ushort4*>(&lA[r * LDT + c4 * 4]) = b;
    }
    __syncthreads();

    const int lane = tid & 63;
    const int w = tid >> 6;
    const int l16 = lane & 15;
    const int koff = (lane >> 4) * 8;

    f32x4 acc[8];
#pragma unroll
    for (int j = 0; j < 8; ++j) acc[j] = (f32x4){0.f, 0.f, 0.f, 0.f};

    const int arow = w * 16 + l16;
#pragma unroll
    for (int kk = 0; kk < 4; ++kk) {
        int kbase = kk * 32 + koff;
        bf16x8 a = *reinterpret_cast<const bf16x8*>(&lA[arow * LDT + kbase]);
#pragma unroll
        for (int j = 0; j < 8; ++j) {
            bf16x8 b = *reinterpret_cast<const bf16x8*>(&lB[(j * 16 + l16) * LDT + kbase]);
            acc[j] = __builtin_amdgcn_mfma_f32_16x16x32_bf16(a, b, acc[j], 0, 0, 0);
        }
    }

    const int crow0 = rowBase + w * 16 + (lane >> 4) * 4;
#pragma unroll
    for (int j = 0; j < 8; ++j) {
        int col = j * 16 + l16;
#pragma unroll
        for (int q = 0; q < 4; ++q) {
            int gr = crow0 + q;
            if (gr < NN) h[(size_t)gr * D + col] = f2bf(acc[j][q]);
        }
    }
}

// ---------------------------------------------------------------------------
// Bucket count: LDS histogram per block, one global atomic per (block,bucket).
// ---------------------------------------------------------------------------
__global__ __launch_bounds__(256) void count_kernel(const int* __restrict__ dst,
                                                    int* __restrict__ bucketCnt) {
    __shared__ int cnt[NB];
    int t = threadIdx.x;
    for (int i = t; i < NB; i += 256) cnt[i] = 0;
    __syncthreads();
    int cb = blockIdx.x * CHUNK;
#pragma unroll
    for (int i = 0; i < CHUNK / 256; ++i) {
        int e = cb + t + 256 * i;
        if (e < NE) atomicAdd(&cnt[dst[e] >> 7], 1);
    }
    __syncthreads();
    for (int i = t; i < NB; i += 256)
        if (cnt[i]) atomicAdd(&bucketCnt[i], cnt[i]);
}

// ---------------------------------------------------------------------------
// Exclusive scan of NB bucket counts (single block, 256 thr x 4 each).
// ---------------------------------------------------------------------------
__global__ __launch_bounds__(256) void scan_kernel(const int* __restrict__ bucketCnt,
                                                   int* __restrict__ bucketPtr,
                                                   int* __restrict__ bucketCursor) {
    __shared__ int lsc[256];
    int t = threadIdx.x;
    int c[4];
    int s = 0;
#pragma unroll
    for (int i = 0; i < 4; ++i) {
        int b = 4 * t + i;
        c[i] = (b < NB) ? bucketCnt[b] : 0;
        s += c[i];
    }
    lsc[t] = s;
    __syncthreads();
    for (int off = 1; off < 256; off <<= 1) {
        int v = (t >= off) ? lsc[t - off] : 0;
        __syncthreads();
        lsc[t] += v;
        __syncthreads();
    }
    int run = lsc[t] - s;
#pragma unroll
    for (int i = 0; i < 4; ++i) {
        int b = 4 * t + i;
        if (b < NB) { bucketPtr[b] = run; bucketCursor[b] = run; }
        run += c[i];
    }
    if (t == 0) bucketPtr[NB] = NE;
}

// ---------------------------------------------------------------------------
// Multi-split scatter: LDS-staged reorder so global writes are per-bucket
// contiguous runs. Record: x = src | (dstLocal<<17), y = val.
// ---------------------------------------------------------------------------
__global__ __launch_bounds__(256) void scatter_kernel(const int* __restrict__ src,
                                                      const int* __restrict__ dst,
                                                      const float* __restrict__ vals,
                                                      int* __restrict__ bucketCursor,
                                                      uint2* __restrict__ ebuf) {
    __shared__ int l_start[NB];
    __shared__ int l_cur[NB];
    __shared__ int l_gbase[NB];
    __shared__ int l_scan[256];
    __shared__ uint2 s_rec[CHUNK];
    __shared__ int s_gd[CHUNK];

    int t = threadIdx.x;
    int cb = blockIdx.x * CHUNK;
    int nloc = min(CHUNK, NE - cb);

    for (int i = t; i < NB; i += 256) l_cur[i] = 0;
    __syncthreads();
#pragma unroll
    for (int i = 0; i < CHUNK / 256; ++i) {
        int e = cb + t + 256 * i;
        if (e < NE) atomicAdd(&l_cur[dst[e] >> 7], 1);
    }
    __syncthreads();

    int c[4];
    int s = 0;
#pragma unroll
    for (int i = 0; i < 4; ++i) {
        int b = 4 * t + i;
        c[i] = (b < NB) ? l_cur[b] : 0;
        s += c[i];
    }
    l_scan[t] = s;
    __syncthreads();
    for (int off = 1; off < 256; off <<= 1) {
        int v = (t >= off) ? l_scan[t - off] : 0;
        __syncthreads();
        l_scan[t] += v;
        __syncthreads();
    }
    int run = l_scan[t] - s;
#pragma unroll
    for (int i = 0; i < 4; ++i) {
        int b = 4 * t + i;
        if (b < NB) {
            l_start[b] = run;
            l_cur[b]   = run;
            l_gbase[b] = c[i] ? atomicAdd(&bucketCursor[b], c[i]) : 0;
        }
        run += c[i];
    }
    __syncthreads();

#pragma unroll
    for (int i = 0; i < CHUNK / 256; ++i) {
        int e = cb + t + 256 * i;
        if (e < NE) {
            int dn = dst[e];
            int b = dn >> 7;
            uint2 rec;
            rec.x = (unsigned int)src[e] | ((unsigned int)(dn & 127) << 17);
            rec.y = __float_as_uint(vals[e]);
            int lofs = atomicAdd(&l_cur[b], 1);
            s_rec[lofs] = rec;
            s_gd[lofs] = l_gbase[b] + (lofs - l_start[b]);
        }
    }
    __syncthreads();

#pragma unroll
    for (int i = 0; i < CHUNK / 256; ++i) {
        int j = t + 256 * i;
        if (j < nloc) ebuf[s_gd[j]] = s_rec[j];
    }
}

// ---------------------------------------------------------------------------
// Pull: one block per bucket. In-LDS counting sort of the bucket's records by
// local dst (128 bins), then wave w accumulates its 16 nodes' contiguous runs
// into registers (lane owns dims {2l,2l+1}). No output atomics. Fused GELU.
// ---------------------------------------------------------------------------
__global__ __launch_bounds__(512) void pull_kernel(const unsigned short* __restrict__ h,
                                                   const int* __restrict__ bucketPtr,
                                                   const uint2* __restrict__ ebuf,
                                                   float* __restrict__ out) {
    __shared__ uint2 srec[CAP];          // 20 KB
    __shared__ int cnt[BSZ];
    __shared__ int start[BSZ + 1];
    __shared__ int cur[BSZ];

    const int t = threadIdx.x;
    const int lane = t & 63;
    const int w = t >> 6;                // 8 waves
    const int b = blockIdx.x;
    const int base = b * BSZ;

    float2 acc[16];
#pragma unroll
    for (int i = 0; i < 16; ++i) acc[i] = (float2){0.f, 0.f};

    const int beg = bucketPtr[b];
    const int end = bucketPtr[b + 1];

    for (int tb = beg; tb < end; tb += CAP) {
        const int n = min(CAP, end - tb);

        if (t < BSZ) cnt[t] = 0;
        __syncthreads();

        // pass 1: histogram of local-dst
        for (int j = t; j < n; j += 512) {
            unsigned int rx = ebuf[tb + j].x;
            atomicAdd(&cnt[(rx >> 17) & 127], 1);
        }
        __syncthreads();

        // wave-0 shuffle scan of the 128 counters -> start/cur
        if (w == 0) {
            int c0 = cnt[2 * lane], c1 = cnt[2 * lane + 1];
            int s = c0 + c1;
            for (int off = 1; off < 64; off <<= 1) {
                int v = __shfl_up(s, off);
                if (lane >= off) s += v;
            }
            int excl = s - c0 - c1;
            start[2 * lane] = excl;
            start[2 * lane + 1] = excl + c0;
            cur[2 * lane] = excl;
            cur[2 * lane + 1] = excl + c0;
            if (lane == 63) start[BSZ] = s;
        }
        __syncthreads();

        // pass 2: scatter records into srec sorted by local dst (L2 re-read)
        for (int j = t; j < n; j += 512) {
            uint2 rec = ebuf[tb + j];
            int dl = (rec.x >> 17) & 127;
            int p = atomicAdd(&cur[dl], 1);
            srec[p] = rec;
        }
        __syncthreads();

        // accumulate: wave w owns nodes [w*16, w*16+16)
#pragma unroll
        for (int i = 0; i < 16; ++i) {
            const int nl = w * 16 + i;
            const int s0 = start[nl];
            const int s1 = start[nl + 1];
            float2 a = acc[i];
            int e = s0;
            for (; e + 1 < s1; e += 2) {
                uint2 r0 = srec[e];
                uint2 r1 = srec[e + 1];
                unsigned int u0 = *reinterpret_cast<const unsigned int*>(
                    h + (size_t)(r0.x & 0x1FFFF) * D + lane * 2);
                unsigned int u1 = *reinterpret_cast<const unsigned int*>(
                    h + (size_t)(r1.x & 0x1FFFF) * D + lane * 2);
                float v0 = __uint_as_float(r0.y);
                float v1 = __uint_as_float(r1.y);
                a.x = fmaf(v0, __uint_as_float(u0 << 16), a.x);
                a.y = fmaf(v0, __uint_as_float(u0 & 0xFFFF0000u), a.y);
                a.x = fmaf(v1, __uint_as_float(u1 << 16), a.x);
                a.y = fmaf(v1, __uint_as_float(u1 & 0xFFFF0000u), a.y);
            }
            if (e < s1) {
                uint2 r0 = srec[e];
                unsigned int u0 = *reinterpret_cast<const unsigned int*>(
                    h + (size_t)(r0.x & 0x1FFFF) * D + lane * 2);
                float v0 = __uint_as_float(r0.y);
                a.x = fmaf(v0, __uint_as_float(u0 << 16), a.x);
                a.y = fmaf(v0, __uint_as_float(u0 & 0xFFFF0000u), a.y);
            }
            acc[i] = a;
        }
        __syncthreads();   // srec reused next tile
    }

    // epilogue: exact GELU + coalesced write
    const float is2 = 0.70710678118654752f;
#pragma unroll
    for (int i = 0; i < 16; ++i) {
        int node = base + w * 16 + i;
        if (node < NN) {
            float a0 = acc[i].x, a1 = acc[i].y;
            a0 = 0.5f * a0 * (1.f + erff(a0 * is2));
            a1 = 0.5f * a1 * (1.f + erff(a1 * is2));
            float2 o; o.x = a0; o.y = a1;
            *reinterpret_cast<float2*>(out + (size_t)node * D + lane * 2) = o;
        }
    }
}

extern "C" void kernel_launch(void* const* d_in, const int* in_sizes, int n_in,
                              void* d_out, int out_size, void* d_ws, size_t ws_size,
                              hipStream_t stream) {
    const float* x    = (const float*)d_in[0];
    const float* W    = (const float*)d_in[1];
    const float* vals = (const float*)d_in[2];
    const int*   src  = (const int*)d_in[3];
    const int*   dst  = (const int*)d_in[4];
    float* out = (float*)d_out;

    char* ws = (char*)d_ws;
    size_t off = 0;
    unsigned short* h = (unsigned short*)(ws + off); off += (size_t)NN * D * 2;
    int* bucketCnt    = (int*)(ws + off); off += ((size_t)NB + 4) * 4;
    int* bucketPtr    = (int*)(ws + off); off += ((size_t)NB + 4) * 4;
    int* bucketCursor = (int*)(ws + off); off += ((size_t)NB + 4) * 4;
    off = (off + 15) & ~(size_t)15;
    uint2* ebuf       = (uint2*)(ws + off); off += (size_t)NE * 8;

    hipMemsetAsync(bucketCnt, 0, ((size_t)NB + 4) * 4, stream);

    mfma_gemm_kernel<<<(NN + BM - 1) / BM, 256, 0, stream>>>(x, W, h);

    count_kernel<<<NBLK, 256, 0, stream>>>(dst, bucketCnt);
    scan_kernel<<<1, 256, 0, stream>>>(bucketCnt, bucketPtr, bucketCursor);
    scatter_kernel<<<NBLK, 256, 0, stream>>>(src, dst, vals, bucketCursor, ebuf);

    pull_kernel<<<NB, 512, 0, stream>>>(h, bucketPtr, ebuf, out);
}

// Round 6
// 203.279 us; speedup vs baseline: 7.0305x; 1.1188x over previous
//
#include <hip/hip_runtime.h>
#include <math.h>

#define NN 100000
#define NE 1600000
#define D 128

#define BSZ 128                         // dst-nodes per bucket
#define NB ((NN + BSZ - 1) / BSZ)       // 782 buckets
#define CHUNK 4096                      // edges per partition block
#define NBLK ((NE + CHUNK - 1) / CHUNK) // 391
#define CAP 2304                        // sorted-records tile per bucket (avg 2046, max ~2200)

#define BM 64            // rows per block in MFMA GEMM
#define LDT 136          // padded LDS row stride (bf16 units)

#define ASG __attribute__((address_space(1)))
#define ASL __attribute__((address_space(3)))

typedef __attribute__((ext_vector_type(8))) short bf16x8;
typedef __attribute__((ext_vector_type(4))) float f32x4;

__device__ __forceinline__ unsigned short f2bf(float f) {
    unsigned int u = __builtin_bit_cast(unsigned int, f);
    unsigned int r = (u + 0x7FFFu + ((u >> 16) & 1u)) >> 16;   // RTNE
    return (unsigned short)r;
}

// ---------------------------------------------------------------------------
// MFMA GEMM: h = bf16(x) @ bf16(W)^T, fp32 accumulate, bf16 output.
// ---------------------------------------------------------------------------
__global__ __launch_bounds__(256) void mfma_gemm_kernel(const float* __restrict__ x,
                                                        const float* __restrict__ W,
                                                        unsigned short* __restrict__ h) {
    __shared__ __align__(16) unsigned short lA[BM * LDT];
    __shared__ __align__(16) unsigned short lB[128 * LDT];
    const int tid = threadIdx.x;
    const int rowBase = blockIdx.x * BM;

#pragma unroll
    for (int i = 0; i < 16; ++i) {
        int f = tid + 256 * i;
        int r = f >> 5, c4 = f & 31;
        float4 v = *reinterpret_cast<const float4*>(W + (size_t)r * D + c4 * 4);
        ushort4 b;
        b.x = f2bf(v.x); b.y = f2bf(v.y); b.z = f2bf(v.z); b.w = f2bf(v.w);
        *reinterpret_cast<ushort4*>(&lB[r * LDT + c4 * 4]) = b;
    }
#pragma unroll
    for (int i = 0; i < 8; ++i) {
        int f = tid + 256 * i;
        int r = f >> 5, c4 = f & 31;
        int gr = rowBase + r;
        float4 v = {0.f, 0.f, 0.f, 0.f};
        if (gr < NN) v = *reinterpret_cast<const float4*>(x + (size_t)gr * D + c4 * 4);
        ushort4 b;
        b.x = f2bf(v.x); b.y = f2bf(v.y); b.z = f2bf(v.z); b.w = f2bf(v.w);
        *reinterpret_cast<ushort4*>(&lA[r * LDT + c4 * 4]) = b;
    }
    __syncthreads();

    const int lane = tid & 63;
    const int w = tid >> 6;
    const int l16 = lane & 15;
    const int koff = (lane >> 4) * 8;

    f32x4 acc[8];
#pragma unroll
    for (int j = 0; j < 8; ++j) acc[j] = (f32x4){0.f, 0.f, 0.f, 0.f};

    const int arow = w * 16 + l16;
#pragma unroll
    for (int kk = 0; kk < 4; ++kk) {
        int kbase = kk * 32 + koff;
        bf16x8 a = *reinterpret_cast<const bf16x8*>(&lA[arow * LDT + kbase]);
#pragma unroll
        for (int j = 0; j < 8; ++j) {
            bf16x8 b = *reinterpret_cast<const bf16x8*>(&lB[(j * 16 + l16) * LDT + kbase]);
            acc[j] = __builtin_amdgcn_mfma_f32_16x16x32_bf16(a, b, acc[j], 0, 0, 0);
        }
    }

    const int crow0 = rowBase + w * 16 + (lane >> 4) * 4;
#pragma unroll
    for (int j = 0; j < 8; ++j) {
        int col = j * 16 + l16;
#pragma unroll
        for (int q = 0; q < 4; ++q) {
            int gr = crow0 + q;
            if (gr < NN) h[(size_t)gr * D + col] = f2bf(acc[j][q]);
        }
    }
}

// ---------------------------------------------------------------------------
// Bucket count: LDS histogram per block, one global atomic per (block,bucket).
// ---------------------------------------------------------------------------
__global__ __launch_bounds__(256) void count_kernel(const int* __restrict__ dst,
                                                    int* __restrict__ bucketCnt) {
    __shared__ int cnt[NB];
    int t = threadIdx.x;
    for (int i = t; i < NB; i += 256) cnt[i] = 0;
    __syncthreads();
    int cb = blockIdx.x * CHUNK;
#pragma unroll
    for (int i = 0; i < CHUNK / 256; ++i) {
        int e = cb + t + 256 * i;
        if (e < NE) atomicAdd(&cnt[dst[e] >> 7], 1);
    }
    __syncthreads();
    for (int i = t; i < NB; i += 256)
        if (cnt[i]) atomicAdd(&bucketCnt[i], cnt[i]);
}

// ---------------------------------------------------------------------------
// Exclusive scan of NB bucket counts (single block, 256 thr x 4 each).
// ---------------------------------------------------------------------------
__global__ __launch_bounds__(256) void scan_kernel(const int* __restrict__ bucketCnt,
                                                   int* __restrict__ bucketPtr,
                                                   int* __restrict__ bucketCursor) {
    __shared__ int lsc[256];
    int t = threadIdx.x;
    int c[4];
    int s = 0;
#pragma unroll
    for (int i = 0; i < 4; ++i) {
        int b = 4 * t + i;
        c[i] = (b < NB) ? bucketCnt[b] : 0;
        s += c[i];
    }
    lsc[t] = s;
    __syncthreads();
    for (int off = 1; off < 256; off <<= 1) {
        int v = (t >= off) ? lsc[t - off] : 0;
        __syncthreads();
        lsc[t] += v;
        __syncthreads();
    }
    int run = lsc[t] - s;
#pragma unroll
    for (int i = 0; i < 4; ++i) {
        int b = 4 * t + i;
        if (b < NB) { bucketPtr[b] = run; bucketCursor[b] = run; }
        run += c[i];
    }
    if (t == 0) bucketPtr[NB] = NE;
}

// ---------------------------------------------------------------------------
// Multi-split scatter: LDS-staged reorder so global writes are per-bucket
// contiguous runs. Record: x = src | (dstLocal<<17), y = val.
// ---------------------------------------------------------------------------
__global__ __launch_bounds__(256) void scatter_kernel(const int* __restrict__ src,
                                                      const int* __restrict__ dst,
                                                      const float* __restrict__ vals,
                                                      int* __restrict__ bucketCursor,
                                                      uint2* __restrict__ ebuf) {
    __shared__ int l_start[NB];
    __shared__ int l_cur[NB];
    __shared__ int l_gbase[NB];
    __shared__ int l_scan[256];
    __shared__ uint2 s_rec[CHUNK];
    __shared__ int s_gd[CHUNK];

    int t = threadIdx.x;
    int cb = blockIdx.x * CHUNK;
    int nloc = min(CHUNK, NE - cb);

    for (int i = t; i < NB; i += 256) l_cur[i] = 0;
    __syncthreads();
#pragma unroll
    for (int i = 0; i < CHUNK / 256; ++i) {
        int e = cb + t + 256 * i;
        if (e < NE) atomicAdd(&l_cur[dst[e] >> 7], 1);
    }
    __syncthreads();

    int c[4];
    int s = 0;
#pragma unroll
    for (int i = 0; i < 4; ++i) {
        int b = 4 * t + i;
        c[i] = (b < NB) ? l_cur[b] : 0;
        s += c[i];
    }
    l_scan[t] = s;
    __syncthreads();
    for (int off = 1; off < 256; off <<= 1) {
        int v = (t >= off) ? l_scan[t - off] : 0;
        __syncthreads();
        l_scan[t] += v;
        __syncthreads();
    }
    int run = l_scan[t] - s;
#pragma unroll
    for (int i = 0; i < 4; ++i) {
        int b = 4 * t + i;
        if (b < NB) {
            l_start[b] = run;
            l_cur[b]   = run;
            l_gbase[b] = c[i] ? atomicAdd(&bucketCursor[b], c[i]) : 0;
        }
        run += c[i];
    }
    __syncthreads();

#pragma unroll
    for (int i = 0; i < CHUNK / 256; ++i) {
        int e = cb + t + 256 * i;
        if (e < NE) {
            int dn = dst[e];
            int b = dn >> 7;
            uint2 rec;
            rec.x = (unsigned int)src[e] | ((unsigned int)(dn & 127) << 17);
            rec.y = __float_as_uint(vals[e]);
            int lofs = atomicAdd(&l_cur[b], 1);
            s_rec[lofs] = rec;
            s_gd[lofs] = l_gbase[b] + (lofs - l_start[b]);
        }
    }
    __syncthreads();

#pragma unroll
    for (int i = 0; i < CHUNK / 256; ++i) {
        int j = t + 256 * i;
        if (j < nloc) ebuf[s_gd[j]] = s_rec[j];
    }
}

// ---------------------------------------------------------------------------
// Pull: one block per bucket. Counting sort by local dst into srec, then each
// wave streams its 16 nodes' contiguous runs through a 2-slot LDS ring filled
// ahead by global_load_lds DMA (8 edges x 256B per slot), waits via counted
// vmcnt(2). Register accumulate, fused GELU. No output atomics.
// ---------------------------------------------------------------------------
__global__ __launch_bounds__(512) void pull_kernel(const unsigned short* __restrict__ h,
                                                   const int* __restrict__ bucketPtr,
                                                   const uint2* __restrict__ ebuf,
                                                   float* __restrict__ out) {
    __shared__ uint2 srec[CAP];                          // 18 KB
    __shared__ int cnt[BSZ];
    __shared__ int start[BSZ + 1];
    __shared__ int cur[BSZ];
    __shared__ __align__(16) unsigned char hbuf[8 * 4096];  // 32 KB: 8 waves x 2 slots x 8 edges x 256 B

    const int t = threadIdx.x;
    const int lane = t & 63;
    const int w = t >> 6;                // 8 waves
    const int b = blockIdx.x;
    const int base = b * BSZ;

    unsigned char* hbufW = hbuf + w * 4096;

    float2 acc[16];
#pragma unroll
    for (int i = 0; i < 16; ++i) acc[i] = (float2){0.f, 0.f};

    const int beg = bucketPtr[b];
    const int end = bucketPtr[b + 1];

    for (int tb = beg; tb < end; tb += CAP) {
        const int n = min(CAP, end - tb);

        if (t < BSZ) cnt[t] = 0;
        __syncthreads();

        // pass 1: histogram of local-dst
        for (int j = t; j < n; j += 512) {
            unsigned int rx = ebuf[tb + j].x;
            atomicAdd(&cnt[(rx >> 17) & 127], 1);
        }
        __syncthreads();

        // wave-0 shuffle scan of the 128 counters -> start/cur
        if (w == 0) {
            int c0 = cnt[2 * lane], c1 = cnt[2 * lane + 1];
            int s = c0 + c1;
            for (int off = 1; off < 64; off <<= 1) {
                int v = __shfl_up(s, off);
                if (lane >= off) s += v;
            }
            int excl = s - c0 - c1;
            start[2 * lane] = excl;
            start[2 * lane + 1] = excl + c0;
            cur[2 * lane] = excl;
            cur[2 * lane + 1] = excl + c0;
            if (lane == 63) start[BSZ] = s;
        }
        __syncthreads();

        // pass 2: scatter records into srec sorted by local dst (L2 re-read)
        for (int j = t; j < n; j += 512) {
            uint2 rec = ebuf[tb + j];
            int dl = (rec.x >> 17) & 127;
            int p = atomicAdd(&cur[dl], 1);
            srec[p] = rec;
        }
        __syncthreads();

        // ---- streamed accumulate: wave w owns nodes [w*16, w*16+16) ----
        const int wbeg = start[w * 16];
        const int wend = start[w * 16 + 16];
        int issued = 0;       // groups of 8 edges issued to the DMA ring
        int consumed = 0;     // groups whose data has been waited on

        // issue one 8-edge group (2 DMA instrs of 4 rows each), clamped
        auto issue_group = [&]() {
            int gbase = wbeg + issued * 8;
#pragma unroll
            for (int q = 0; q < 2; ++q) {
                int idx = gbase + q * 4 + (lane >> 4);
                idx = min(idx, wend - 1);
                unsigned int rx = reinterpret_cast<const unsigned int*>(&srec[idx])[0];
                unsigned int srcn = rx & 0x1FFFFu;
                const unsigned char* gp = reinterpret_cast<const unsigned char*>(h)
                                          + (size_t)srcn * 256 + (size_t)((lane & 15) * 16);
                unsigned char* lp = hbufW + (issued & 1) * 2048 + q * 1024;
                __builtin_amdgcn_global_load_lds((ASG const unsigned int*)(const void*)gp,
                                                 (ASL unsigned int*)(void*)lp, 16, 0, 0);
            }
            issued++;
        };

        if (wend > wbeg) { issue_group(); issue_group(); }

#pragma unroll
        for (int i = 0; i < 16; ++i) {
            const int s1 = start[w * 16 + i + 1];
            int e = start[w * 16 + i];
            float2 a = acc[i];
            for (; e < s1; ++e) {
                if (e >= wbeg + consumed * 8) {
                    // entering group `consumed`: slot of group consumed+1's
                    // partner (consumed-1) is fully drained -> safe to refill
                    if (consumed) issue_group();
                    asm volatile("s_waitcnt vmcnt(2)" ::: "memory");
                    consumed++;
                }
                int le = e - wbeg;
                unsigned int hw = *reinterpret_cast<const unsigned int*>(
                    hbufW + ((le >> 3) & 1) * 2048 + (le & 7) * 256 + lane * 4);
                float v = __uint_as_float(reinterpret_cast<const unsigned int*>(&srec[e])[1]);
                a.x = fmaf(v, __uint_as_float(hw << 16), a.x);
                a.y = fmaf(v, __uint_as_float(hw & 0xFFFF0000u), a.y);
            }
            acc[i] = a;
        }
        __syncthreads();   // drains all DMA (incl. dangling prefetch); srec reused
    }

    // epilogue: exact GELU + coalesced write
    const float is2 = 0.70710678118654752f;
#pragma unroll
    for (int i = 0; i < 16; ++i) {
        int node = base + w * 16 + i;
        if (node < NN) {
            float a0 = acc[i].x, a1 = acc[i].y;
            a0 = 0.5f * a0 * (1.f + erff(a0 * is2));
            a1 = 0.5f * a1 * (1.f + erff(a1 * is2));
            float2 o; o.x = a0; o.y = a1;
            *reinterpret_cast<float2*>(out + (size_t)node * D + lane * 2) = o;
        }
    }
}

extern "C" void kernel_launch(void* const* d_in, const int* in_sizes, int n_in,
                              void* d_out, int out_size, void* d_ws, size_t ws_size,
                              hipStream_t stream) {
    const float* x    = (const float*)d_in[0];
    const float* W    = (const float*)d_in[1];
    const float* vals = (const float*)d_in[2];
    const int*   src  = (const int*)d_in[3];
    const int*   dst  = (const int*)d_in[4];
    float* out = (float*)d_out;

    char* ws = (char*)d_ws;
    size_t off = 0;
    unsigned short* h = (unsigned short*)(ws + off); off += (size_t)NN * D * 2;
    int* bucketCnt    = (int*)(ws + off); off += ((size_t)NB + 4) * 4;
    int* bucketPtr    = (int*)(ws + off); off += ((size_t)NB + 4) * 4;
    int* bucketCursor = (int*)(ws + off); off += ((size_t)NB + 4) * 4;
    off = (off + 15) & ~(size_t)15;
    uint2* ebuf       = (uint2*)(ws + off); off += (size_t)NE * 8;

    hipMemsetAsync(bucketCnt, 0, ((size_t)NB + 4) * 4, stream);

    mfma_gemm_kernel<<<(NN + BM - 1) / BM, 256, 0, stream>>>(x, W, h);

    count_kernel<<<NBLK, 256, 0, stream>>>(dst, bucketCnt);
    scan_kernel<<<1, 256, 0, stream>>>(bucketCnt, bucketPtr, bucketCursor);
    scatter_kernel<<<NBLK, 256, 0, stream>>>(src, dst, vals, bucketCursor, ebuf);

    pull_kernel<<<NB, 512, 0, stream>>>(h, bucketPtr, ebuf, out);
}

// Round 7
// 190.540 us; speedup vs baseline: 7.5005x; 1.0669x over previous
//
#include <hip/hip_runtime.h>
#include <math.h>

#define NN 100000
#define NE 1600000
#define D 128

#define BSZ 128                         // dst-nodes per bucket
#define NB 782                          // ceil(NN/BSZ)
#define CAPB 3072                       // fixed ebuf capacity per bucket (mean 2046, +22 sigma)
#define CHUNK 4096                      // edges per partition block
#define NBLK ((NE + CHUNK - 1) / CHUNK) // 391
#define CAP 2304                        // sorted-records tile per bucket

#define BM 64            // rows per block in MFMA GEMM
#define LDT 136          // padded LDS row stride for x tile (bf16 units)

#define ASG __attribute__((address_space(1)))
#define ASL __attribute__((address_space(3)))

typedef __attribute__((ext_vector_type(8))) short bf16x8;
typedef __attribute__((ext_vector_type(4))) float f32x4;

__device__ __forceinline__ unsigned short f2bf(float f) {
    unsigned int u = __builtin_bit_cast(unsigned int, f);
    unsigned int r = (u + 0x7FFFu + ((u >> 16) & 1u)) >> 16;   // RTNE
    return (unsigned short)r;
}

// ---------------------------------------------------------------------------
// W precompute: fp32 W -> bf16, stored SLOT-SWIZZLED in global so gemm can
// DMA it linearly into LDS and read fragments conflict-free:
//   Wswz[row][slot ^ (row&15)] = bf16(W[row][slot*8 .. slot*8+7])   (16B slots)
// ---------------------------------------------------------------------------
__global__ __launch_bounds__(256) void wconv_kernel(const float* __restrict__ W,
                                                    unsigned short* __restrict__ Wswz) {
    int i = blockIdx.x * 256 + threadIdx.x;   // 2048 threads total
    int r = i >> 4, s = i & 15;
    const float4* wp = reinterpret_cast<const float4*>(W + (size_t)r * D + s * 8);
    float4 v0 = wp[0], v1 = wp[1];
    ushort4 b0, b1;
    b0.x = f2bf(v0.x); b0.y = f2bf(v0.y); b0.z = f2bf(v0.z); b0.w = f2bf(v0.w);
    b1.x = f2bf(v1.x); b1.y = f2bf(v1.y); b1.z = f2bf(v1.z); b1.w = f2bf(v1.w);
    int so = s ^ (r & 15);
    unsigned short* op = Wswz + (size_t)r * D + so * 8;
    *reinterpret_cast<ushort4*>(op)     = b0;
    *reinterpret_cast<ushort4*>(op + 4) = b1;
}

// ---------------------------------------------------------------------------
// MFMA GEMM: h = bf16(x) @ bf16(W)^T, fp32 accumulate, bf16 output.
// W tile arrives by global_load_lds DMA (linear, zero VALU); fragment reads
// un-swizzle with the same XOR (2-way bank alias = free). x tile staged with
// conversion into a padded LDS tile as before.
// ---------------------------------------------------------------------------
__global__ __launch_bounds__(256) void mfma_gemm_kernel(const float* __restrict__ x,
                                                        const unsigned short* __restrict__ Wswz,
                                                        unsigned short* __restrict__ h) {
    __shared__ __align__(16) unsigned short lA[BM * LDT];    // 17408 B
    __shared__ __align__(16) unsigned short lB[128 * 128];   // 32768 B, swizzled content
    const int tid = threadIdx.x;
    const int lane = tid & 63;
    const int w = tid >> 6;
    const int rowBase = blockIdx.x * BM;

    // DMA Wswz -> lB: 32 wave-instrs of 1 KB (8 per wave), linear copy.
#pragma unroll
    for (int q = 0; q < 8; ++q) {
        const unsigned char* gp = reinterpret_cast<const unsigned char*>(Wswz)
                                  + (size_t)((w * 8 + q) * 1024 + lane * 16);
        unsigned char* lp = reinterpret_cast<unsigned char*>(lB) + (w * 8 + q) * 1024;
        __builtin_amdgcn_global_load_lds((ASG const unsigned int*)(const void*)gp,
                                         (ASL unsigned int*)(void*)lp, 16, 0, 0);
    }

    // Stage x tile (64x128 fp32 -> bf16): 8 float4 per thread.
#pragma unroll
    for (int i = 0; i < 8; ++i) {
        int f = tid + 256 * i;
        int r = f >> 5, c4 = f & 31;
        int gr = rowBase + r;
        float4 v = {0.f, 0.f, 0.f, 0.f};
        if (gr < NN) v = *reinterpret_cast<const float4*>(x + (size_t)gr * D + c4 * 4);
        ushort4 b;
        b.x = f2bf(v.x); b.y = f2bf(v.y); b.z = f2bf(v.z); b.w = f2bf(v.w);
        *reinterpret_cast<ushort4*>(&lA[r * LDT + c4 * 4]) = b;
    }
    __syncthreads();   // drains vmcnt (DMA) + lgkm

    const int l16 = lane & 15;
    const int koff = (lane >> 4) * 8;          // bf16 units
    const int kx16 = (lane >> 4) * 16;         // byte offset of slot within row

    f32x4 acc[8];
#pragma unroll
    for (int j = 0; j < 8; ++j) acc[j] = (f32x4){0.f, 0.f, 0.f, 0.f};

    const int arow = w * 16 + l16;
    const int bxor = l16 << 4;                 // (row&15)<<4 == l16<<4
#pragma unroll
    for (int kk = 0; kk < 4; ++kk) {
        int kbase = kk * 32 + koff;
        bf16x8 a = *reinterpret_cast<const bf16x8*>(&lA[arow * LDT + kbase]);
        int kbyte = kk * 64 + kx16;
#pragma unroll
        for (int j = 0; j < 8; ++j) {
            int row = j * 16 + l16;
            bf16x8 b = *reinterpret_cast<const bf16x8*>(
                reinterpret_cast<const unsigned char*>(lB) + row * 256 + (kbyte ^ bxor));
            acc[j] = __builtin_amdgcn_mfma_f32_16x16x32_bf16(a, b, acc[j], 0, 0, 0);
        }
    }

    const int crow0 = rowBase + w * 16 + (lane >> 4) * 4;
#pragma unroll
    for (int j = 0; j < 8; ++j) {
        int col = j * 16 + l16;
#pragma unroll
        for (int q = 0; q < 4; ++q) {
            int gr = crow0 + q;
            if (gr < NN) h[(size_t)gr * D + col] = f2bf(acc[j][q]);
        }
    }
}

// ---------------------------------------------------------------------------
// Multi-split scatter into fixed-capacity bucket regions (no pre-count/scan).
// LDS-staged reorder so global writes are per-bucket contiguous runs.
// Record: x = src | (dstLocal<<17), y = val. cursor[b] ends as bucket count.
// ---------------------------------------------------------------------------
__global__ __launch_bounds__(256) void scatter_kernel(const int* __restrict__ src,
                                                      const int* __restrict__ dst,
                                                      const float* __restrict__ vals,
                                                      int* __restrict__ bucketCursor,
                                                      uint2* __restrict__ ebuf) {
    __shared__ int l_start[NB];
    __shared__ int l_cur[NB];
    __shared__ int l_gbase[NB];
    __shared__ int l_scan[256];
    __shared__ uint2 s_rec[CHUNK];
    __shared__ int s_gd[CHUNK];

    int t = threadIdx.x;
    int cb = blockIdx.x * CHUNK;
    int nloc = min(CHUNK, NE - cb);

    for (int i = t; i < NB; i += 256) l_cur[i] = 0;
    __syncthreads();
#pragma unroll
    for (int i = 0; i < CHUNK / 256; ++i) {
        int e = cb + t + 256 * i;
        if (e < NE) atomicAdd(&l_cur[dst[e] >> 7], 1);
    }
    __syncthreads();

    int c[4];
    int s = 0;
#pragma unroll
    for (int i = 0; i < 4; ++i) {
        int b = 4 * t + i;
        c[i] = (b < NB) ? l_cur[b] : 0;
        s += c[i];
    }
    l_scan[t] = s;
    __syncthreads();
    for (int off = 1; off < 256; off <<= 1) {
        int v = (t >= off) ? l_scan[t - off] : 0;
        __syncthreads();
        l_scan[t] += v;
        __syncthreads();
    }
    int run = l_scan[t] - s;
#pragma unroll
    for (int i = 0; i < 4; ++i) {
        int b = 4 * t + i;
        if (b < NB) {
            l_start[b] = run;
            l_cur[b]   = run;
            l_gbase[b] = b * CAPB + (c[i] ? atomicAdd(&bucketCursor[b], c[i]) : 0);
        }
        run += c[i];
    }
    __syncthreads();

#pragma unroll
    for (int i = 0; i < CHUNK / 256; ++i) {
        int e = cb + t + 256 * i;
        if (e < NE) {
            int dn = dst[e];
            int b = dn >> 7;
            uint2 rec;
            rec.x = (unsigned int)src[e] | ((unsigned int)(dn & 127) << 17);
            rec.y = __float_as_uint(vals[e]);
            int lofs = atomicAdd(&l_cur[b], 1);
            s_rec[lofs] = rec;
            s_gd[lofs] = l_gbase[b] + (lofs - l_start[b]);
        }
    }
    __syncthreads();

#pragma unroll
    for (int i = 0; i < CHUNK / 256; ++i) {
        int j = t + 256 * i;
        if (j < nloc) ebuf[s_gd[j]] = s_rec[j];
    }
}

// ---------------------------------------------------------------------------
// Pull: one block per bucket. Counting sort by local dst into srec, then each
// wave streams its 16 nodes' contiguous runs through a 2-slot LDS ring filled
// by global_load_lds DMA (4 edges x 256B per slot, 1 instr/group), counted
// vmcnt(1) waits. 35.6 KB LDS -> 4 blocks/CU. Fused GELU, no output atomics.
// ---------------------------------------------------------------------------
__global__ __launch_bounds__(512) void pull_kernel(const unsigned short* __restrict__ h,
                                                   const int* __restrict__ bucketCursor,
                                                   const uint2* __restrict__ ebuf,
                                                   float* __restrict__ out) {
    __shared__ uint2 srec[CAP];                          // 18 KB
    __shared__ int cnt[BSZ];
    __shared__ int start[BSZ + 1];
    __shared__ int cur[BSZ];
    __shared__ __align__(16) unsigned char hbuf[8 * 2048];  // 16 KB: 8 waves x 2 slots x 4 edges x 256 B

    const int t = threadIdx.x;
    const int lane = t & 63;
    const int w = t >> 6;                // 8 waves
    const int b = blockIdx.x;
    const int base = b * BSZ;

    unsigned char* hbufW = hbuf + w * 2048;

    float2 acc[16];
#pragma unroll
    for (int i = 0; i < 16; ++i) acc[i] = (float2){0.f, 0.f};

    const int n = bucketCursor[b];
    const uint2* ebase = ebuf + (size_t)b * CAPB;

    for (int tb = 0; tb < n; tb += CAP) {
        const int nt = min(CAP, n - tb);
        const uint2* eb = ebase + tb;

        if (t < BSZ) cnt[t] = 0;
        __syncthreads();

        // pass 1: histogram of local-dst
        for (int j = t; j < nt; j += 512) {
            unsigned int rx = eb[j].x;
            atomicAdd(&cnt[(rx >> 17) & 127], 1);
        }
        __syncthreads();

        // wave-0 shuffle scan of the 128 counters -> start/cur
        if (w == 0) {
            int c0 = cnt[2 * lane], c1 = cnt[2 * lane + 1];
            int s = c0 + c1;
            for (int off = 1; off < 64; off <<= 1) {
                int v = __shfl_up(s, off);
                if (lane >= off) s += v;
            }
            int excl = s - c0 - c1;
            start[2 * lane] = excl;
            start[2 * lane + 1] = excl + c0;
            cur[2 * lane] = excl;
            cur[2 * lane + 1] = excl + c0;
            if (lane == 63) start[BSZ] = s;
        }
        __syncthreads();

        // pass 2: scatter records into srec sorted by local dst
        for (int j = t; j < nt; j += 512) {
            uint2 rec = eb[j];
            int dl = (rec.x >> 17) & 127;
            int p = atomicAdd(&cur[dl], 1);
            srec[p] = rec;
        }
        __syncthreads();

        // ---- streamed accumulate: wave w owns nodes [w*16, w*16+16) ----
        const int wbeg = start[w * 16];
        const int wend = start[w * 16 + 16];
        int issued = 0;
        int consumed = 0;

        auto issue_group = [&]() {
            int idx = min(wbeg + issued * 4 + (lane >> 4), wend - 1);
            unsigned int rx = reinterpret_cast<const unsigned int*>(&srec[idx])[0];
            const unsigned char* gp = reinterpret_cast<const unsigned char*>(h)
                                      + (size_t)(rx & 0x1FFFFu) * 256 + (size_t)((lane & 15) * 16);
            unsigned char* lp = hbufW + (issued & 1) * 1024;
            __builtin_amdgcn_global_load_lds((ASG const unsigned int*)(const void*)gp,
                                             (ASL unsigned int*)(void*)lp, 16, 0, 0);
            issued++;
        };

        if (wend > wbeg) { issue_group(); issue_group(); }
        int next_refill = wbeg;

#pragma unroll
        for (int i = 0; i < 16; ++i) {
            const int s1 = start[w * 16 + i + 1];
            float2 a = acc[i];
            for (int e = start[w * 16 + i]; e < s1; ++e) {
                if (e >= next_refill) {
                    if (consumed) issue_group();
                    asm volatile("s_waitcnt vmcnt(1)" ::: "memory");
                    __builtin_amdgcn_sched_barrier(0);
                    consumed++;
                    next_refill += 4;
                }
                int le = e - wbeg;
                unsigned int hw = *reinterpret_cast<const unsigned int*>(
                    hbufW + ((le >> 2) & 1) * 1024 + (le & 3) * 256 + lane * 4);
                float v = __uint_as_float(reinterpret_cast<const unsigned int*>(&srec[e])[1]);
                a.x = fmaf(v, __uint_as_float(hw << 16), a.x);
                a.y = fmaf(v, __uint_as_float(hw & 0xFFFF0000u), a.y);
            }
            acc[i] = a;
        }
        __syncthreads();   // drains dangling DMA; srec reused next tile
    }

    // epilogue: exact GELU + coalesced write
    const float is2 = 0.70710678118654752f;
#pragma unroll
    for (int i = 0; i < 16; ++i) {
        int node = base + w * 16 + i;
        if (node < NN) {
            float a0 = acc[i].x, a1 = acc[i].y;
            a0 = 0.5f * a0 * (1.f + erff(a0 * is2));
            a1 = 0.5f * a1 * (1.f + erff(a1 * is2));
            float2 o; o.x = a0; o.y = a1;
            *reinterpret_cast<float2*>(out + (size_t)node * D + lane * 2) = o;
        }
    }
}

extern "C" void kernel_launch(void* const* d_in, const int* in_sizes, int n_in,
                              void* d_out, int out_size, void* d_ws, size_t ws_size,
                              hipStream_t stream) {
    const float* x    = (const float*)d_in[0];
    const float* W    = (const float*)d_in[1];
    const float* vals = (const float*)d_in[2];
    const int*   src  = (const int*)d_in[3];
    const int*   dst  = (const int*)d_in[4];
    float* out = (float*)d_out;

    // ws: h bf16 (25.6MB) | bucketCursor | Wswz (32KB) | ebuf (NB*CAPB*8 = 19.2MB)
    char* ws = (char*)d_ws;
    size_t off = 0;
    unsigned short* h    = (unsigned short*)(ws + off); off += (size_t)NN * D * 2;
    int* bucketCursor    = (int*)(ws + off);            off += ((size_t)NB + 4) * 4;
    off = (off + 15) & ~(size_t)15;
    unsigned short* Wswz = (unsigned short*)(ws + off); off += (size_t)D * D * 2;
    off = (off + 15) & ~(size_t)15;
    uint2* ebuf          = (uint2*)(ws + off);          off += (size_t)NB * CAPB * 8;

    hipMemsetAsync(bucketCursor, 0, ((size_t)NB + 4) * 4, stream);

    wconv_kernel<<<8, 256, 0, stream>>>(W, Wswz);
    mfma_gemm_kernel<<<(NN + BM - 1) / BM, 256, 0, stream>>>(x, Wswz, h);
    scatter_kernel<<<NBLK, 256, 0, stream>>>(src, dst, vals, bucketCursor, ebuf);
    pull_kernel<<<NB, 512, 0, stream>>>(h, bucketCursor, ebuf, out);
}